// Round 13
// baseline (4017.750 us; speedup 1.0000x reference)
//
#include <hip/hip_runtime.h>
#include <hip/hip_bf16.h>
#include <math.h>

#define NN 50000
#define NE 600000
#define ET (NN + NE)               // 650000 edges incl. self-loops
#define FILLB ((ET + 255) / 256)   // 2540 blocks for hist
#define NTILE (NN / 16)            // 3125 gemm tiles (exact)
#define GEMMB ((NTILE + 3) / 4)    // 782 blocks of 4 waves
#define NBUCK 49                   // ceil(NN/1024) dst-buckets
#define BCAP 16384                 // bucket capacity (mean 13312, sigma~111)
#define AGGB (NN / 4)              // 12500 aggregate blocks (exact)

typedef __hip_bfloat16 bf16;
typedef __attribute__((ext_vector_type(8))) short bf16x8;
typedef __attribute__((ext_vector_type(4))) float f32x4;

static __device__ inline unsigned short f2bf(float f) {
    union { __hip_bfloat16 h; unsigned short u; } v;
    v.h = __float2bfloat16(f);
    return v.u;
}
static __device__ inline float bf2f(bf16 h) { return __bfloat162float(h); }

// ------------------------------------------------ hist + bucket-scatter + weight-convert
// Level-1 of the CSR build: append (src,dst) to coarse dst-buckets (sequential-ish
// 8B appends -> no write amplification), count degrees. Plus weight transpose.
__global__ void k_hist_wconv(const int* __restrict__ ei, int* __restrict__ deg,
                             int* __restrict__ bcnt, int2* __restrict__ bucket,
                             const float* __restrict__ W1, const float* __restrict__ Wm,
                             const float* __restrict__ W2, short* __restrict__ WT1,
                             short* __restrict__ WTm, short* __restrict__ WT2) {
    int b = blockIdx.x;
    if (b < FILLB) {
        int e = b * 256 + threadIdx.x;
        if (e < ET) {
            int s = (e < NE) ? ei[e] : (e - NE);
            int d = (e < NE) ? ei[NE + e] : (e - NE);
            atomicAdd(&deg[d], 1);
            int bk = d >> 10;
            int pos = atomicAdd(&bcnt[bk], 1);
            if (pos < BCAP) bucket[(size_t)bk * BCAP + pos] = make_int2(s, d);
        }
    } else {
        int idx = (b - FILLB) * 256 + threadIdx.x;
        if (idx < 16384) {                       // W1 [128][128] -> WT1 [128][128]
            int d = idx >> 7, k = idx & 127;
            WT1[idx] = (short)f2bf(W1[k * 128 + d]);
        } else if (idx < 32768) {                // Wm
            int i2 = idx - 16384;
            int d = i2 >> 7, k = i2 & 127;
            WTm[i2] = (short)f2bf(Wm[k * 128 + d]);
        } else if (idx < 40960) {                // W2 [128][64] -> WT2 [64][128]
            int i3 = idx - 32768;
            int d = i3 >> 7, k = i3 & 127;
            WT2[i3] = (short)f2bf(W2[k * 64 + d]);
        }
    }
}

// ------------------------------------------------ degree scan (per-1024 chunk)
__global__ void k_scan_local(const int* __restrict__ deg, int* __restrict__ tmp,
                             int* __restrict__ csum) {
    __shared__ int wsum[16];
    int i = blockIdx.x * 1024 + threadIdx.x;
    int lane = threadIdx.x & 63, wid = threadIdx.x >> 6;
    int x = (i < NN) ? deg[i] : 0;
    for (int off = 1; off < 64; off <<= 1) {
        int y = __shfl_up(x, off);
        if (lane >= off) x += y;
    }
    if (lane == 63) wsum[wid] = x;
    __syncthreads();
    if (wid == 0) {
        int t = (lane < 16) ? wsum[lane] : 0;
        for (int off = 1; off < 16; off <<= 1) {
            int y = __shfl_up(t, off);
            if (lane >= off) t += y;
        }
        if (lane < 16) wsum[lane] = t;
    }
    __syncthreads();
    if (wid > 0) x += wsum[wid - 1];
    if (i < NN) tmp[i] = x;                        // inclusive within chunk
    if (threadIdx.x == 1023) csum[blockIdx.x] = x; // chunk total
}

// rowptr with inline chunk-prefix scan (nchunks=49 <= 64; redundant per block, trivial)
__global__ void k_rowptr(const int* __restrict__ tmp, const int* __restrict__ csum,
                         int* __restrict__ rowptr, int nchunks) {
    __shared__ int pref[64];
    if (threadIdx.x < 64) {
        int lane = threadIdx.x;
        int v = (lane < nchunks) ? csum[lane] : 0;
        for (int off = 1; off < 64; off <<= 1) {
            int y = __shfl_up(v, off);
            if (lane >= off) v += y;
        }
        pref[lane] = v;
    }
    __syncthreads();
    int i = blockIdx.x * blockDim.x + threadIdx.x;
    if (i == 0) rowptr[0] = 0;
    if (i < NN) {
        int chunk = i >> 10;
        int off = (chunk > 0) ? pref[chunk - 1] : 0;
        rowptr[i + 1] = tmp[i] + off;
    }
}

// ------------------------------------------------ MFMA GEMM body (K=128)
// One wave per 16-row tile. MODE 0: fp32 input. MODE 1: bf16 + fused elu(bn).
// MODE 2: MODE 1 + fused residual elu(bn2(x2)). C/D: row=(lane>>4)*4+reg, col=lane&15.
template <int D, int HF, int MODE>
static __device__ __forceinline__ void gemm_body(int tile, int lane,
    const float* __restrict__ Xf, const bf16* __restrict__ X1, const float2* __restrict__ ss1,
    const bf16* __restrict__ X2, const float2* __restrict__ ss2,
    const short* __restrict__ WT, bf16* __restrict__ Hout,
    const float* __restrict__ a_s, const float* __restrict__ a_d,
    float* __restrict__ S, float* __restrict__ Dv) {
    constexpr int K = 128;
    constexpr int NT = D / 16;
    int rb = tile * 16;
    int m = lane & 15, kg = lane >> 4;

    f32x4 acc[NT];
#pragma unroll
    for (int n = 0; n < NT; n++) acc[n] = (f32x4){0.f, 0.f, 0.f, 0.f};

#pragma unroll
    for (int k0 = 0; k0 < K; k0 += 32) {
        int cb = k0 + kg * 8;
        bf16x8 a;
        if constexpr (MODE == 0) {
            const float* xp = Xf + (size_t)(rb + m) * K + cb;
            float4 f0 = *reinterpret_cast<const float4*>(xp);
            float4 f1 = *reinterpret_cast<const float4*>(xp + 4);
            a[0] = (short)f2bf(f0.x); a[1] = (short)f2bf(f0.y);
            a[2] = (short)f2bf(f0.z); a[3] = (short)f2bf(f0.w);
            a[4] = (short)f2bf(f1.x); a[5] = (short)f2bf(f1.y);
            a[6] = (short)f2bf(f1.z); a[7] = (short)f2bf(f1.w);
        } else {
            bf16x8 r1 = *reinterpret_cast<const bf16x8*>(X1 + (size_t)(rb + m) * K + cb);
            bf16x8 r2;
            if constexpr (MODE == 2)
                r2 = *reinterpret_cast<const bf16x8*>(X2 + (size_t)(rb + m) * K + cb);
#pragma unroll
            for (int j = 0; j < 8; j++) {
                float2 p1 = ss1[cb + j];
                bf16 b1; *(short*)&b1 = r1[j];
                float v = p1.x * bf2f(b1) + p1.y;
                v = (v > 0.f) ? v : (__expf(v) - 1.f);
                if constexpr (MODE == 2) {
                    float2 p2 = ss2[cb + j];
                    bf16 b2; *(short*)&b2 = r2[j];
                    float v2 = p2.x * bf2f(b2) + p2.y;
                    v2 = (v2 > 0.f) ? v2 : (__expf(v2) - 1.f);
                    v += v2;
                }
                a[j] = (short)f2bf(v);
            }
        }
#pragma unroll
        for (int n = 0; n < NT; n++) {
            bf16x8 b = *reinterpret_cast<const bf16x8*>(WT + (size_t)(n * 16 + m) * K + cb);
            acc[n] = __builtin_amdgcn_mfma_f32_16x16x32_bf16(a, b, acc[n], 0, 0, 0);
        }
    }

    float asv[NT], adv[NT];
#pragma unroll
    for (int n = 0; n < NT; n++) {
        asv[n] = a_s[n * 16 + m];
        adv[n] = a_d[n * 16 + m];
    }
#pragma unroll
    for (int r = 0; r < 4; r++) {
        int row = rb + kg * 4 + r;
#pragma unroll
        for (int n = 0; n < NT; n++)
            Hout[(size_t)row * D + n * 16 + m] = __float2bfloat16(acc[n][r]);
        if constexpr (HF == 1) {
            float sa = 0.f, da = 0.f;
#pragma unroll
            for (int n = 0; n < NT; n++) {
                sa += acc[n][r] * asv[n];
                da += acc[n][r] * adv[n];
            }
            for (int off = 1; off < 16; off <<= 1) {
                sa += __shfl_xor(sa, off);
                da += __shfl_xor(da, off);
            }
            if (m == 0) { S[row] = sa; Dv[row] = da; }
        } else {
            // C == 16: head index == col-tile index n
#pragma unroll
            for (int n = 0; n < NT; n++) {
                float sa = acc[n][r] * asv[n];
                float da = acc[n][r] * adv[n];
                for (int off = 1; off < 16; off <<= 1) {
                    sa += __shfl_xor(sa, off);
                    da += __shfl_xor(da, off);
                }
                if (m == 0) { S[row * HF + n] = sa; Dv[row * HF + n] = da; }
            }
        }
    }
}

template <int D, int HF, int MODE>
__global__ __launch_bounds__(64) void k_gemm_mfma(const float* Xf, const bf16* X1,
                                                  const float2* ss1, const bf16* X2,
                                                  const float2* ss2, const short* WT,
                                                  bf16* Hout, const float* a_s,
                                                  const float* a_d, float* S, float* Dv) {
    gemm_body<D, HF, MODE>(blockIdx.x, threadIdx.x, Xf, X1, ss1, X2, ss2, WT, Hout, a_s, a_d, S, Dv);
}

// ------------------------------------------------ CSR fill (level-2, bucketed) + layer-1 GEMM
// One block per bucket: per-node LDS cursors seeded from rowptr; scatter confined
// to the bucket's contiguous ~53KB csr window (L2-resident -> ~1x write traffic).
__global__ __launch_bounds__(256) void k_fill_gemm1(const int* __restrict__ bcnt,
                                                    const int2* __restrict__ bucket,
                                                    const int* __restrict__ rowptr,
                                                    int* __restrict__ csr,
                                                    const float* __restrict__ x,
                                                    const short* __restrict__ WT1,
                                                    bf16* __restrict__ Hout,
                                                    const float* __restrict__ as1,
                                                    const float* __restrict__ ad1,
                                                    float* __restrict__ S, float* __restrict__ Dv) {
    if (blockIdx.x < NBUCK) {
        __shared__ int cur[1024];
        int base = blockIdx.x << 10;
        for (int i = threadIdx.x; i < 1024; i += 256)
            cur[i] = (base + i < NN) ? rowptr[base + i] : 0;
        __syncthreads();
        int nb = min(bcnt[blockIdx.x], BCAP);
        for (int idx = threadIdx.x; idx < nb; idx += 256) {
            int2 sd = bucket[(size_t)blockIdx.x * BCAP + idx];
            int pos = atomicAdd(&cur[sd.y - base], 1);
            csr[pos] = sd.x;
        }
        return;
    }
    int tile = (blockIdx.x - NBUCK) * 4 + (threadIdx.x >> 6);
    if (tile >= NTILE) return;
    gemm_body<128, 8, 0>(tile, threadIdx.x & 63, x, nullptr, nullptr, nullptr, nullptr,
                         WT1, Hout, as1, ad1, S, Dv);
}

// K=64, D=40 (layer 3): one node per 64-thread block; fused elu(bn(x)) input + H=1 scores.
__global__ void k_gemm_small(const bf16* __restrict__ X, const float2* __restrict__ ss,
                             const float* __restrict__ W, bf16* __restrict__ Hout,
                             const float* __restrict__ a_s, const float* __restrict__ a_d,
                             float* __restrict__ S, float* __restrict__ Dv) {
    __shared__ float xs[64];
    int n = blockIdx.x, t = threadIdx.x;
    {
        float2 p = ss[t];
        float v = p.x * bf2f(X[n * 64 + t]) + p.y;
        xs[t] = (v > 0.f) ? v : (__expf(v) - 1.f);
    }
    __syncthreads();
    float acc = 0.f;
    if (t < 40) {
#pragma unroll
        for (int k = 0; k < 64; k++) acc += xs[k] * W[k * 40 + t];
        Hout[n * 40 + t] = __float2bfloat16(acc);
    }
    float sa = (t < 40) ? acc * a_s[t] : 0.f;
    float da = (t < 40) ? acc * a_d[t] : 0.f;
    for (int off = 32; off; off >>= 1) {
        sa += __shfl_xor(sa, off);
        da += __shfl_xor(da, off);
    }
    if (t == 0) {
        S[n] = sa;
        Dv[n] = da;
    }
}

// ------------------------------------------------ aggregation (one-pass) + fused BN stats
// out = sum_e w_e*h_e / sum_e w_e, w = exp(leaky(S[src]+Dv[dst])). Denominator
// accumulated alongside (no phase-1/LDS cache). 4-way unrolled (8-way regressed R8).
// Epilogue: per-block LDS (sum,sq) reduction -> 8-shadow global atomics; FIN: last
// block (device-scope counter, atomicAdd(p,0) coherent re-read) emits (scale,shift).
template <int H, int C, int D, bool FIN>
__global__ __launch_bounds__(256) void k_aggregate(const bf16* __restrict__ Hb,
                                                   const float* __restrict__ S,
                                                   const float* __restrict__ Dv,
                                                   const int* __restrict__ rowptr,
                                                   const int* __restrict__ csr,
                                                   bf16* __restrict__ Out,
                                                   float* __restrict__ shad,
                                                   int* __restrict__ cnt,
                                                   const float* __restrict__ g,
                                                   const float* __restrict__ be,
                                                   float2* __restrict__ ss) {
    __shared__ float bsum[D], bsq[D];
    for (int t = threadIdx.x; t < D; t += 256) { bsum[t] = 0.f; bsq[t] = 0.f; }
    __syncthreads();

    int node = blockIdx.x * 4 + (threadIdx.x >> 6);  // AGGB*4 == NN exactly, no guard
    int lane = threadIdx.x & 63;
    int r0 = rowptr[node], r1 = rowptr[node + 1];
    int cnt_e = r1 - r0;
    constexpr int EPI = (D > 64) ? 1 : 2;  // edges per iteration
    constexpr int LP = 64 / EPI;           // lanes per edge
    int sub = lane / LP;
    int j = lane % LP;                     // column pair (2j, 2j+1)
    bool act = (2 * j) < D;
    const int h_l = act ? (2 * j) / C : 0; // lane-constant head
    float dn_l = Dv[node * H + h_l];

    float ax = 0.f, ay = 0.f, den = 0.f;
    int k = sub;
    for (; k + 3 * EPI < cnt_e; k += 4 * EPI) {
        int uu[4];
        float svv[4];
        unsigned pp[4];
#pragma unroll
        for (int i = 0; i < 4; i++) uu[i] = csr[r0 + k + i * EPI];
#pragma unroll
        for (int i = 0; i < 4; i++) svv[i] = S[(size_t)uu[i] * H + h_l];
#pragma unroll
        for (int i = 0; i < 4; i++)
            pp[i] = act ? *reinterpret_cast<const unsigned*>(Hb + (size_t)uu[i] * D + 2 * j) : 0u;
#pragma unroll
        for (int i = 0; i < 4; i++) {
            float e = svv[i] + dn_l;
            e = fmaxf(e, 0.2f * e);        // leaky_relu
            float w = __expf(e);
            den += w;
            ax += w * __uint_as_float(pp[i] << 16);
            ay += w * __uint_as_float(pp[i] & 0xffff0000u);
        }
    }
    for (; k < cnt_e; k += EPI) {
        int u = csr[r0 + k];
        float e = S[(size_t)u * H + h_l] + dn_l;
        e = fmaxf(e, 0.2f * e);
        float w = __expf(e);
        den += w;
        unsigned pv = act ? *reinterpret_cast<const unsigned*>(Hb + (size_t)u * D + 2 * j) : 0u;
        ax += w * __uint_as_float(pv << 16);
        ay += w * __uint_as_float(pv & 0xffff0000u);
    }
    if (EPI == 2) {
        ax += __shfl_xor(ax, 32);
        ay += __shfl_xor(ay, 32);
        den += __shfl_xor(den, 32);
    }
    if (act && lane < LP) {
        float inv = 1.f / (den + 1e-16f);
        float o0 = ax * inv, o1 = ay * inv;
        unsigned o = (unsigned)f2bf(o0) | ((unsigned)f2bf(o1) << 16);
        *reinterpret_cast<unsigned*>(Out + (size_t)node * D + 2 * j) = o;
        atomicAdd(&bsum[2 * j], o0);
        atomicAdd(&bsum[2 * j + 1], o1);
        atomicAdd(&bsq[2 * j], o0 * o0);
        atomicAdd(&bsq[2 * j + 1], o1 * o1);
    }
    __syncthreads();
    // shadow layout: [8][256] floats per layer-set; sum at [sh][c], sq at [sh][128+c]
    float* sh = shad + (size_t)(blockIdx.x & 7) * 256;
    for (int t = threadIdx.x; t < D; t += 256) {
        atomicAdd(&sh[t], bsum[t]);
        atomicAdd(&sh[128 + t], bsq[t]);
    }
    if constexpr (FIN) {
        __shared__ int lastFlag;
        __threadfence();
        __syncthreads();
        if (threadIdx.x == 0)
            lastFlag = (atomicAdd(cnt, 1) == (int)gridDim.x - 1) ? 1 : 0;
        __syncthreads();
        if (lastFlag) {
            for (int c = threadIdx.x; c < D; c += 256) {
                float su = 0.f, sq = 0.f;
#pragma unroll
                for (int s8 = 0; s8 < 8; s8++) {
                    su += atomicAdd(&shad[s8 * 256 + c], 0.f);
                    sq += atomicAdd(&shad[s8 * 256 + 128 + c], 0.f);
                }
                float mu = su * (1.f / NN);
                float var = sq * (1.f / NN) - mu * mu;
                float sc = g[c] * rsqrtf(var + 1e-5f);
                ss[c] = make_float2(sc, be[c] - mu * sc);
            }
        }
    }
}

// Layer 3: fused BN + log_softmax over 40 classes; one wave per node. bf16 in, fp32 out.
// BN stats come from the 8 shadow copies written by the preceding aggregate.
__global__ void k_bn_logsoftmax(const bf16* __restrict__ X, const float* __restrict__ shad,
                                const float* __restrict__ g, const float* __restrict__ be,
                                float* __restrict__ Out) {
    int node = (blockIdx.x * blockDim.x + threadIdx.x) >> 6;
    int lane = threadIdx.x & 63;
    if (node >= NN) return;
    float bnv = 0.f, v = -1e30f;
    if (lane < 40) {
        float su = 0.f, sq = 0.f;
#pragma unroll
        for (int s8 = 0; s8 < 8; s8++) {
            su += shad[s8 * 256 + lane];
            sq += shad[s8 * 256 + 128 + lane];
        }
        float mu = su * (1.f / NN);
        float var = sq * (1.f / NN) - mu * mu;
        float sc = g[lane] * rsqrtf(var + 1e-5f);
        bnv = sc * (bf2f(X[node * 40 + lane]) - mu) + be[lane];
        v = bnv;
    }
    float m = v;
    for (int off = 32; off; off >>= 1) m = fmaxf(m, __shfl_xor(m, off));
    float ex = (lane < 40) ? expf(bnv - m) : 0.f;
    for (int off = 32; off; off >>= 1) ex += __shfl_xor(ex, off);
    float lse = m + logf(ex);
    if (lane < 40) Out[node * 40 + lane] = bnv - lse;
}

// ------------------------------------------------ launch (13 dispatches)
extern "C" void kernel_launch(void* const* d_in, const int* in_sizes, int n_in,
                              void* d_out, int out_size, void* d_ws, size_t ws_size,
                              hipStream_t stream) {
    (void)in_sizes; (void)n_in; (void)out_size; (void)ws_size;
    const float* x   = (const float*)d_in[0];
    const int*   ei  = (const int*)d_in[1];
    const float* W1  = (const float*)d_in[2];
    const float* as1 = (const float*)d_in[3];
    const float* ad1 = (const float*)d_in[4];
    const float* g1  = (const float*)d_in[6];
    const float* be1 = (const float*)d_in[7];
    const float* Wm  = (const float*)d_in[8];
    const float* asm_ = (const float*)d_in[9];
    const float* adm = (const float*)d_in[10];
    const float* gm  = (const float*)d_in[12];
    const float* bem = (const float*)d_in[13];
    const float* W2  = (const float*)d_in[14];
    const float* as2 = (const float*)d_in[15];
    const float* ad2 = (const float*)d_in[16];
    const float* g2  = (const float*)d_in[18];
    const float* be2 = (const float*)d_in[19];
    const float* W3  = (const float*)d_in[20];
    const float* as3 = (const float*)d_in[21];
    const float* ad3 = (const float*)d_in[22];
    const float* g3  = (const float*)d_in[24];
    const float* be3 = (const float*)d_in[25];
    float* out = (float*)d_out;
    // GAT biases b1/bm/b2/b3 cancel inside the immediately-following BN (mean-subtract).

    char* ws = (char*)d_ws;
    size_t off = 0;
    auto alloc = [&](size_t b) {
        void* p = ws + off;
        off = (off + b + 255) & ~(size_t)255;
        return p;
    };
    int* rowptr = (int*)alloc((NN + 1) * 4);
    int* csr    = (int*)alloc((size_t)ET * 4);
    // single zeroed region: deg | bcnt(64) | shadows(4 sets x 8 x 256 f32) | cnt(4)
    const size_t ZB = (size_t)NN * 4 + 64 * 4 + 4 * 8 * 256 * 4 + 16;
    char* zb    = (char*)alloc(ZB);
    int* deg    = (int*)zb;
    int* bcnt   = (int*)(zb + (size_t)NN * 4);
    float* shad = (float*)(zb + (size_t)NN * 4 + 64 * 4);   // per set: 2048 floats
    int* cnt    = (int*)(zb + (size_t)NN * 4 + 64 * 4 + 4 * 8 * 256 * 4);
    int* tmp    = (int*)alloc(NN * 4);
    int* csum   = (int*)alloc(256 * 4);
    int2* bucket = (int2*)alloc((size_t)NBUCK * BCAP * 8);
    bf16* Hbf   = (bf16*)alloc((size_t)NN * 128 * 2);
    bf16* AG1   = (bf16*)alloc((size_t)NN * 128 * 2);
    bf16* AG2   = (bf16*)alloc((size_t)NN * 128 * 2);
    bf16* AG3   = (bf16*)alloc((size_t)NN * 64 * 2);
    bf16* AG4   = (bf16*)alloc((size_t)NN * 40 * 2);
    float* S    = (float*)alloc((size_t)NN * 8 * 4);
    float* Dv   = (float*)alloc((size_t)NN * 8 * 4);
    float2* ss1 = (float2*)alloc(128 * 8);
    float2* ssM = (float2*)alloc(128 * 8);
    float2* ss2 = (float2*)alloc(64 * 8);
    short* WT1  = (short*)alloc(128 * 128 * 2);
    short* WTm  = (short*)alloc(128 * 128 * 2);
    short* WT2  = (short*)alloc(128 * 64 * 2);

    const int nchunks = (NN + 1023) / 1024;  // 49

    // 1. one memset for all zeroed state
    hipMemsetAsync(zb, 0, ZB, stream);
    // 2. degree histogram + bucket scatter + weight transpose/convert
    k_hist_wconv<<<FILLB + 160, 256, 0, stream>>>(ei, deg, bcnt, bucket, W1, Wm, W2, WT1, WTm, WT2);
    // 3-4. prefix scan -> rowptr (chunk scan inlined)
    k_scan_local<<<nchunks, 1024, 0, stream>>>(deg, tmp, csum);
    k_rowptr<<<(NN + 255) / 256, 256, 0, stream>>>(tmp, csum, rowptr, nchunks);
    // 5. bucketed CSR fill + layer-1 GEMM (independent work, one dispatch)
    k_fill_gemm1<<<NBUCK + GEMMB, 256, 0, stream>>>(bcnt, bucket, rowptr, csr, x, WT1, Hbf,
                                                    as1, ad1, S, Dv);
    // 6. layer-1 aggregate + BN stats/finalize -> AG1, ss1
    k_aggregate<8, 16, 128, true><<<AGGB, 256, 0, stream>>>(Hbf, S, Dv, rowptr, csr, AG1,
                                                            shad + 0 * 2048, cnt + 0, g1, be1, ss1);
    // 7-8. mid layer (input = elu(bn1(AG1)) fused; H=1 scores fused) -> AG2, ssM
    k_gemm_mfma<128, 1, 1><<<NTILE, 64, 0, stream>>>(nullptr, AG1, ss1, nullptr, nullptr, WTm,
                                                     Hbf, asm_, adm, S, Dv);
    k_aggregate<1, 128, 128, true><<<AGGB, 256, 0, stream>>>(Hbf, S, Dv, rowptr, csr, AG2,
                                                             shad + 1 * 2048, cnt + 1, gm, bem, ssM);
    // 9-10. layer 2 (input = elu(bnM(AG2)) + elu(bn1(AG1)) fused) -> AG3, ss2
    k_gemm_mfma<64, 4, 2><<<NTILE, 64, 0, stream>>>(nullptr, AG2, ssM, AG1, ss1, WT2,
                                                    Hbf, as2, ad2, S, Dv);
    k_aggregate<4, 16, 64, true><<<AGGB, 256, 0, stream>>>(Hbf, S, Dv, rowptr, csr, AG3,
                                                           shad + 2 * 2048, cnt + 2, g2, be2, ss2);
    // 11-13. layer 3 (input = elu(bn2(AG3)) fused into small GEMM); BN + log_softmax
    k_gemm_small<<<NN, 64, 0, stream>>>(AG3, ss2, W3, Hbf, as3, ad3, S, Dv);
    k_aggregate<1, 40, 40, false><<<AGGB, 256, 0, stream>>>(Hbf, S, Dv, rowptr, csr, AG4,
                                                            shad + 3 * 2048, nullptr, nullptr,
                                                            nullptr, nullptr);
    k_bn_logsoftmax<<<AGGB, 256, 0, stream>>>(AG4, shad + 3 * 2048, g3, be3, out);
}